// Round 1
// baseline (187.887 us; speedup 1.0000x reference)
//
#include <hip/hip_runtime.h>
#include <stdint.h>

#define NTOK 16384   // B*S = 4*4096
#define DIN 512
#define DOUT 512
#define KE 8
#define BM 128
#define BN 128
#define BK 64

#define GATE_BLOCKS 512            // 32 tokens/block (4 waves x 8 tokens)
#define WCONV_BLOCKS 1024          // 2M elements / (256*8)

typedef unsigned short u16;
typedef u16 u16x8 __attribute__((ext_vector_type(8)));
typedef __bf16 bf16x8 __attribute__((ext_vector_type(8)));
typedef float f32x4 __attribute__((ext_vector_type(4)));

__device__ __forceinline__ u16 f2bf(float f) {
  union { float f; unsigned u; } v; v.f = f;
  unsigned r = v.u + 0x7FFFu + ((v.u >> 16) & 1u);   // RNE; inputs are finite
  return (u16)(r >> 16);
}

// async global->LDS, 16B per lane; LDS dest is wave-uniform base + lane*16
#define GLOAD_LDS16(gp, lp)                                              \
  __builtin_amdgcn_global_load_lds(                                     \
      (__attribute__((address_space(1))) void*)(gp),                    \
      (__attribute__((address_space(3))) void*)(lp), 16, 0, 0)

// ---------------------------------------------------------------------------
// Kernel 1 (merged prologue):
//  blocks [0, GATE_BLOCKS): gating softmax + x fp32->bf16 cast (32 tok/block)
//  blocks [GATE_BLOCKS, +WCONV_BLOCKS): expert-weight fp32->bf16 cast
// v2: mixer weights held in REGISTERS (64 floats/lane) -- no LDS staging,
// no ds_read bank conflicts, 4x fewer gate blocks re-reading mw.
// Coeffs written TRANSPOSED: coeffsT[e][tok]  (GEMM folds load float4).
// ---------------------------------------------------------------------------
__global__ __launch_bounds__(256) void prologue_kernel(
    const float* __restrict__ x, const float* __restrict__ mw,
    const float* __restrict__ mb, const float* __restrict__ ew,
    u16* __restrict__ xbf, u16* __restrict__ wbf, float* __restrict__ coeffsT) {
  const int tid = threadIdx.x;

  if (blockIdx.x >= GATE_BLOCKS) {
    // ---- weight cast: 8 elements/thread ----
    const size_t i =
        ((size_t)(blockIdx.x - GATE_BLOCKS) * 256 + tid) * 8;
    const float4 a = *(const float4*)&ew[i];
    const float4 b = *(const float4*)&ew[i + 4];
    u16x8 p;
    p[0] = f2bf(a.x); p[1] = f2bf(a.y); p[2] = f2bf(a.z); p[3] = f2bf(a.w);
    p[4] = f2bf(b.x); p[5] = f2bf(b.y); p[6] = f2bf(b.z); p[7] = f2bf(b.w);
    *(u16x8*)&wbf[i] = p;
    return;
  }

  // ---- gating + x cast ----
  const int wave = tid >> 6, lane = tid & 63;

  // mixer weight slice for this lane, in registers: mwr[k][j] = mw[k][lane*8+j]
  float mwr[KE][8];
#pragma unroll
  for (int k = 0; k < KE; ++k) {
    const float* wr = &mw[k * DIN + lane * 8];
    const float4 w0 = *(const float4*)wr;
    const float4 w1 = *(const float4*)(wr + 4);
    mwr[k][0] = w0.x; mwr[k][1] = w0.y; mwr[k][2] = w0.z; mwr[k][3] = w0.w;
    mwr[k][4] = w1.x; mwr[k][5] = w1.y; mwr[k][6] = w1.z; mwr[k][7] = w1.w;
  }
  float mbr[KE];
#pragma unroll
  for (int k = 0; k < KE; ++k) mbr[k] = mb[k];

  for (int t = 0; t < 8; ++t) {
    const int tok = blockIdx.x * 32 + wave * 8 + t;
    const float* xr = x + (size_t)tok * DIN + lane * 8;
    const float4 xa = *(const float4*)xr;
    const float4 xb = *(const float4*)(xr + 4);

    u16x8 p;
    p[0] = f2bf(xa.x); p[1] = f2bf(xa.y); p[2] = f2bf(xa.z); p[3] = f2bf(xa.w);
    p[4] = f2bf(xb.x); p[5] = f2bf(xb.y); p[6] = f2bf(xb.z); p[7] = f2bf(xb.w);
    *(u16x8*)(xbf + (size_t)tok * DIN + lane * 8) = p;

    float lg[KE];
#pragma unroll
    for (int k = 0; k < KE; ++k) {
      lg[k] = xa.x * mwr[k][0] + xa.y * mwr[k][1] + xa.z * mwr[k][2] +
              xa.w * mwr[k][3] + xb.x * mwr[k][4] + xb.y * mwr[k][5] +
              xb.z * mwr[k][6] + xb.w * mwr[k][7];
    }
#pragma unroll
    for (int off = 32; off; off >>= 1)
#pragma unroll
      for (int k = 0; k < KE; ++k) lg[k] += __shfl_xor(lg[k], off);

#pragma unroll
    for (int k = 0; k < KE; ++k) lg[k] += mbr[k];
    float mx = lg[0];
#pragma unroll
    for (int k = 1; k < KE; ++k) mx = fmaxf(mx, lg[k]);
    float s = 0.f;
#pragma unroll
    for (int k = 0; k < KE; ++k) { lg[k] = __expf(lg[k] - mx); s += lg[k]; }
    const float inv = 1.f / s;
    if (lane == 0) {
#pragma unroll
      for (int k = 0; k < KE; ++k) coeffsT[(size_t)k * NTOK + tok] = lg[k] * inv;
    }
  }
}

// ---------------------------------------------------------------------------
// Kernel 2: main MoE GEMM. v2: BM=128 BN=128 BK=64, 4 waves (2x2), per-wave
// 64x64 output via 4x4 fragments of 16x16x32 MFMA.
// Why: rocprof showed MfmaUtil 31% / VALU 14% / HBM 8% -> LDS-read-BW bound.
// 2x4 frags read 0.75 KB LDS per MFMA (ceiling ~41% util); 4x4 frags read
// 0.5 KB/MFMA (ceiling ~62%). Grid 512 = exactly 2 blocks/CU, no dispatch
// tail (old 1024@3/CU ran 1.33 rounds -> 24.5% measured occupancy).
// LDS 64 KB (2-tile double-buffer) -> 2 blocks/CU. part+acc = 128 VGPR,
// __launch_bounds__(256,2) caps at 256.
// - XCD swizzle (bijective, 512%8==0): each XCD pair owns one n-column so
//   its 1 MB B-slice stays L2-resident; m contiguous within XCD.
// - XOR-swizzled LDS (proven 0 conflicts): slot s of row r = chunk s^(r&7),
//   via pre-swizzled global source col (both-sides rule).
// - Bias fused into per-expert fold: acc += c*(part + beta_e[col]).
// ---------------------------------------------------------------------------
__global__ __launch_bounds__(256, 2) void moe_gemm_kernel(
    const u16* __restrict__ xbf, const u16* __restrict__ wbf,
    const float* __restrict__ coeffsT, const float* __restrict__ ebias,
    float* __restrict__ out) {
  __shared__ __align__(16) u16 As[2][BM * BK];   // 2 x 16 KB
  __shared__ __align__(16) u16 Bs[2][BN * BK];   // 2 x 16 KB

  const int tid = threadIdx.x;
  const int wave = tid >> 6, lane = tid & 63;

  // XCD swizzle: b&7 = xcd (round-robin dispatch), s = intra-XCD sequence.
  // n-col = xcd>>1 (2 XCDs share a column; B slice 1 MB resident in L2);
  // m-block = (xcd&1)*64 + s  (contiguous m per XCD, streams A).
  const int b = blockIdx.x;
  const int xcd = b & 7, s = b >> 3;            // s in [0,64)
  const int m0 = ((xcd & 1) * 64 + s) * BM;
  const int n0 = (xcd >> 1) * BN;

  const int wm = (wave >> 1) * 64;   // wave's row offset: {0,64}
  const int wn = (wave & 1) * 64;    // wave's col offset: {0,64}

  // staging: each GLOAD covers 8 rows x 64 cols (1 KB). lane -> row lrow;
  // SOURCE col chunk XOR-swizzled: LDS slot s of row r = global chunk s^(r&7).
  const int lrow = lane >> 3;
  const int scol = ((lane & 7) ^ lrow) * 8;
  const u16* aBase = xbf + (size_t)(m0 + wave * 32 + lrow) * DIN + scol;
  const u16* bBase0 = wbf + (size_t)(n0 + wave * 32 + lrow) * DIN + scol;

  const int frow = lane & 15;
  const int fsel = lane >> 4;
  const int fxor = lane & 7;
  const int quad = lane >> 4;

  f32x4 acc[4][4] = {};

  for (int e = 0; e < KE; ++e) {
    f32x4 part[4][4] = {};
    const u16* bE = bBase0 + (size_t)e * (DOUT * DIN);

    for (int h = 0; h < 4; ++h) {   // 4 rounds x 2 K-tiles = 512 K
      __syncthreads();   // previous round's LDS reads done
      // stage tiles 2h (buf 0) and 2h+1 (buf 1): 16 GLOADs back-to-back
#pragma unroll
      for (int buf = 0; buf < 2; ++buf) {
        const size_t koff = (size_t)(h * 2 + buf) * 64;
#pragma unroll
        for (int j = 0; j < 4; ++j)
          GLOAD_LDS16(aBase + (size_t)(j * 8) * DIN + koff,
                      &As[buf][(wave * 32 + j * 8) * BK]);
#pragma unroll
        for (int j = 0; j < 4; ++j)
          GLOAD_LDS16(bE + (size_t)(j * 8) * DIN + koff,
                      &Bs[buf][(wave * 32 + j * 8) * BK]);
      }
      __syncthreads();   // drain -> both buffers valid

#pragma unroll
      for (int buf = 0; buf < 2; ++buf) {
#pragma unroll
        for (int ks = 0; ks < 2; ++ks) {
          const int slot = (ks * 4 + fsel) ^ fxor;   // rows mult of 8
          bf16x8 af[4], bfv[4];
#pragma unroll
          for (int mi = 0; mi < 4; ++mi)
            af[mi] = *(const bf16x8*)&As[buf][(wm + mi * 16 + frow) * BK + slot * 8];
#pragma unroll
          for (int ni = 0; ni < 4; ++ni)
            bfv[ni] = *(const bf16x8*)&Bs[buf][(wn + ni * 16 + frow) * BK + slot * 8];
#pragma unroll
          for (int mi = 0; mi < 4; ++mi)
#pragma unroll
            for (int ni = 0; ni < 4; ++ni)
              part[mi][ni] = __builtin_amdgcn_mfma_f32_16x16x32_bf16(
                  af[mi], bfv[ni], part[mi][ni], 0, 0, 0);
        }
      }
    }

    // fold expert into acc with fused bias: acc += c[row,e]*(part + beta[e,col])
    // C/D layout (m89/m91): col = lane&15, row = quad*4 + reg
    float bv[4];
#pragma unroll
    for (int ni = 0; ni < 4; ++ni)
      bv[ni] = ebias[e * DOUT + n0 + wn + ni * 16 + frow];
    const float* cT = coeffsT + (size_t)e * NTOK + m0;
#pragma unroll
    for (int mi = 0; mi < 4; ++mi) {
      const float4 c4 = *(const float4*)&cT[wm + mi * 16 + quad * 4];
#pragma unroll
      for (int ni = 0; ni < 4; ++ni) {
        acc[mi][ni][0] += c4.x * (part[mi][ni][0] + bv[ni]);
        acc[mi][ni][1] += c4.y * (part[mi][ni][1] + bv[ni]);
        acc[mi][ni][2] += c4.z * (part[mi][ni][2] + bv[ni]);
        acc[mi][ni][3] += c4.w * (part[mi][ni][3] + bv[ni]);
      }
    }
  }

  // epilogue: plain store (bias already folded)
#pragma unroll
  for (int mi = 0; mi < 4; ++mi) {
    const int rb = wm + mi * 16 + quad * 4;
#pragma unroll
    for (int j = 0; j < 4; ++j) {
      const int row = rb + j;
#pragma unroll
      for (int ni = 0; ni < 4; ++ni) {
        const int col = wn + ni * 16 + frow;
        out[(size_t)(m0 + row) * DOUT + n0 + col] = acc[mi][ni][j];
      }
    }
  }
}

// ---------------------------------------------------------------------------
extern "C" void kernel_launch(void* const* d_in, const int* in_sizes, int n_in,
                              void* d_out, int out_size, void* d_ws,
                              size_t ws_size, hipStream_t stream) {
  (void)in_sizes; (void)n_in; (void)out_size; (void)ws_size;
  const float* x  = (const float*)d_in[0];   // [4,4096,512]
  const float* ew = (const float*)d_in[1];   // [8,512,512]
  const float* eb = (const float*)d_in[2];   // [8,512]
  const float* mw = (const float*)d_in[3];   // [8,512]
  const float* mb = (const float*)d_in[4];   // [8]
  float* out = (float*)d_out;                // [4,4096,512]

  // workspace layout: xbf 16 MB | wbf 4 MB | coeffsT 0.5 MB  (~20.5 MB)
  u16* xbf = (u16*)d_ws;
  u16* wbf = (u16*)((char*)d_ws + (size_t)NTOK * DIN * 2);
  float* coeffsT =
      (float*)((char*)d_ws + (size_t)NTOK * DIN * 2 + (size_t)KE * DOUT * DIN * 2);

  hipLaunchKernelGGL(prologue_kernel, dim3(GATE_BLOCKS + WCONV_BLOCKS),
                     dim3(256), 0, stream, x, mw, mb, ew, xbf, wbf, coeffsT);
  hipLaunchKernelGGL(moe_gemm_kernel, dim3((NTOK / BM) * (DOUT / BN)), dim3(256),
                     0, stream, xbf, wbf, coeffsT, eb, out);
}